// Round 7
// baseline (419.774 us; speedup 1.0000x reference)
//
#include <hip/hip_runtime.h>
#include <hip/hip_cooperative_groups.h>

namespace cg = cooperative_groups;

#define BB 32
#define NN 2048
#define DD 65
#define HH 64
#define ST 68                // padded leading dim (16B-aligned float4 frags)
#define TILE (DD * ST)       // 4420 floats per padded 65x65 matrix
#define CC 32                // x chunks per batch (64 rows each)
#define WST 66               // compact LDS stride for WkL / WvT

// LDS layout (bytes) -- union across phases, 39440 B total (<= 40960 for
// 4 blocks/CU residency):
//   region0 @ 0      (17680): P1 Xl | P2b GL | P3 Tl
//   region1 @ 17680  (17408): P2b WkL->WvT   | P3 Xl/Ol
//   Mr      @ 35088  (2176), Rr @ 37264 (2176)   [P2b]
#define OFF1 17680
#define OFFM 35088
#define OFFR 37264
#define SMEM_BYTES 39440

__device__ __forceinline__ float4 f4add(float4 a, float4 b) {
  return make_float4(a.x + b.x, a.y + b.y, a.z + b.z, a.w + b.w);
}

// async global->LDS, 16B per lane, wave-uniform LDS base + lane*16
#define GL2LDS(g, l)                                             \
  __builtin_amdgcn_global_load_lds(                              \
      (const __attribute__((address_space(1))) void*)(g),        \
      (__attribute__((address_space(3))) void*)(l), 16, 0, 0)

// ===========================================================================
// fused: all 4 phases in ONE cooperative launch (1024 blocks x 256 thr,
// 4 blocks/CU resident). Kills 3 kernel-dispatch boundaries; P3 re-reads the
// x chunk its block staged in P1 (same XCD -> L2-warm). Phase bodies are the
// round-5-verified kernels verbatim (same arithmetic order -> same absmax).
// ===========================================================================
__global__ __launch_bounds__(256, 4) void fused(
    const float* __restrict__ x, const float* __restrict__ Wq,
    const float* __restrict__ Wk, const float* __restrict__ Wv,
    float* __restrict__ P, float* __restrict__ G, float* __restrict__ Tm,
    float* __restrict__ out) {
  __shared__ __align__(16) char smem[SMEM_BYTES];
  const int t = (int)threadIdx.x;
  const int bid = (int)blockIdx.x;

  // ================= P1: partial Gram P[b][c] (R5 k1) =================
  {
    float* Xl = (float*)smem;  // [64][ST]
    const int tx = t & 15, ty = t >> 4;
    const int b = bid >> 5, c = bid & 31;
    const float4* src4 =
        (const float4*)(x + ((size_t)b * NN + (size_t)c * 64) * DD);

    {  // f4 staging: 1040 float4, 5 slots/thread, all in flight
      float4 tmp[5];
#pragma unroll
      for (int q = 0; q < 5; q++) {
        const int i4 = t + 256 * q;
        if (i4 < 1040) tmp[q] = src4[i4];
      }
#pragma unroll
      for (int q = 0; q < 5; q++) {
        const int i4 = t + 256 * q;
        if (i4 < 1040) {
          const int f = 4 * i4;
          const float vv[4] = {tmp[q].x, tmp[q].y, tmp[q].z, tmp[q].w};
#pragma unroll
          for (int j = 0; j < 4; j++) {
            const int r = (f + j) / DD, cc = (f + j) - r * DD;
            Xl[r * ST + cc] = vv[j];
          }
        }
      }
    }
    __syncthreads();

    float g[4][4] = {};
    float g64[4] = {};
    float gcc = 0.f;
    for (int n = 0; n < 64; n++) {
      float rowf[4], colf[4];
      *(float4*)rowf = *(const float4*)&Xl[n * ST + 4 * ty];
      *(float4*)colf = *(const float4*)&Xl[n * ST + 4 * tx];
      const float x64 = Xl[n * ST + 64];  // broadcast, conflict-free
#pragma unroll
      for (int r = 0; r < 4; r++)
#pragma unroll
        for (int cc = 0; cc < 4; cc++)
          g[r][cc] = fmaf(rowf[r], colf[cc], g[r][cc]);
#pragma unroll
      for (int cc = 0; cc < 4; cc++) g64[cc] = fmaf(x64, colf[cc], g64[cc]);
      gcc = fmaf(x64, x64, gcc);
    }
    float* Pp = P + (size_t)bid * TILE;
#pragma unroll
    for (int r = 0; r < 4; r++)
      *(float4*)&Pp[(4 * ty + r) * ST + 4 * tx] = *(float4*)g[r];
    if (ty == 0) {
      *(float4*)&Pp[64 * ST + 4 * tx] = *(float4*)g64;  // G[64][j]
#pragma unroll
      for (int cc = 0; cc < 4; cc++)
        Pp[(4 * tx + cc) * ST + 64] = g64[cc];          // G[i][64] symmetry
      if (tx == 0) Pp[64 * ST + 64] = gcc;
    }
  }
  cg::this_grid().sync();

  // ================= P2a: reduce P -> G (R5 kred), 160 blocks ============
  if (bid < BB * 5) {
    const int b = bid / 5, s = bid - b * 5;
    const int Q = TILE / 4;  // 1105
    const int i4 = s * 256 + t;
    if (i4 < Q) {
      const float4* Pb = (const float4*)(P + (size_t)b * CC * TILE);
      float4 acc = make_float4(0.f, 0.f, 0.f, 0.f);
#pragma unroll
      for (int grp = 0; grp < 4; grp++) {
        float4 v[8];
#pragma unroll
        for (int cc = 0; cc < 8; cc++)
          v[cc] = Pb[(size_t)(8 * grp + cc) * Q + i4];
#pragma unroll
        for (int stp = 4; stp >= 1; stp >>= 1)
#pragma unroll
          for (int cc = 0; cc < stp; cc++) v[cc] = f4add(v[cc], v[cc + stp]);
        acc = f4add(acc, v[0]);
      }
      ((float4*)(G + (size_t)b * TILE))[i4] = acc;
    }
  }
  cg::this_grid().sync();

  // ================= P2b: T = (Wq^T Wk) G Wv^T (row-parallel), 288 blocks
  // LDS-compacted: Wq read from global (L1-hot broadcast), WkL stride-66,
  // WvT overlaid on WkL after the R phase. Loop arithmetic identical to R5.
  if (bid < BB * 9) {
    float* GL = (float*)smem;              // [65][ST]
    float* WkL = (float*)(smem + OFF1);    // [64][WST] -> later WvT [65][WST]
    float* Mr = (float*)(smem + OFFM);     // [8][ST]
    float* Rr = (float*)(smem + OFFR);     // [8][ST]
    const int tx = t & 31, ty = t >> 5;
    const int b = bid / 9, rg = bid - b * 9;
    const int i = 8 * rg + ty;
    const bool alive = (i < DD);
    const int ic = alive ? i : 0;

    {  // stage WkL (scatter to stride-66) + GL (straight f4 copy)
      const float4* Wk4 = (const float4*)Wk;                       // 1040 f4
      const float4* Gb4 = (const float4*)(G + (size_t)b * TILE);   // 1105 f4
      float4 tk[5], tG[5];
#pragma unroll
      for (int q = 0; q < 5; q++) {
        const int i4 = t + 256 * q;
        if (i4 < 1040) tk[q] = Wk4[i4];
      }
#pragma unroll
      for (int q = 0; q < 5; q++) {
        const int i4 = t + 256 * q;
        if (i4 < TILE / 4) tG[q] = Gb4[i4];
      }
#pragma unroll
      for (int q = 0; q < 5; q++) {
        const int i4 = t + 256 * q;
        if (i4 < 1040) {
          const int f = 4 * i4;
          const float vv[4] = {tk[q].x, tk[q].y, tk[q].z, tk[q].w};
#pragma unroll
          for (int j = 0; j < 4; j++) {
            const int r = (f + j) / DD, cc = (f + j) - r * DD;
            WkL[r * WST + cc] = vv[j];
          }
        }
      }
#pragma unroll
      for (int q = 0; q < 5; q++) {
        const int i4 = t + 256 * q;
        if (i4 < TILE / 4) ((float4*)GL)[i4] = tG[q];
      }
    }
    __syncthreads();

    {  // M phase: Wq from global (broadcast), Wk from LDS
      float m0 = 0.f, m1 = 0.f, m2 = 0.f;
#pragma unroll 4
      for (int h = 0; h < HH; h++) {
        const float wq = Wq[h * DD + ic];
        m0 = fmaf(wq, WkL[h * WST + tx], m0);
        m1 = fmaf(wq, WkL[h * WST + tx + 32], m1);
        m2 = fmaf(wq, WkL[h * WST + 64], m2);
      }
      if (alive) {
        Mr[ty * ST + tx] = m0;
        Mr[ty * ST + tx + 32] = m1;
        if (tx == 0) Mr[ty * ST + 64] = m2;
      }
    }
    __syncthreads();

    {  // R phase
      float r0 = 0.f, r1 = 0.f, r2 = 0.f;
      for (int k = 0; k < DD; k++) {
        const float mm = Mr[ty * ST + k];
        r0 = fmaf(mm, GL[k * ST + tx], r0);
        r1 = fmaf(mm, GL[k * ST + tx + 32], r1);
        r2 = fmaf(mm, GL[k * ST + 64], r2);
      }
      if (alive) {
        Rr[ty * ST + tx] = r0;
        Rr[ty * ST + tx + 32] = r1;
        if (tx == 0) Rr[ty * ST + 64] = r2;
      }
    }
    __syncthreads();

    {  // stage WvT (transposed) over the WkL region
      float tv[17];
#pragma unroll
      for (int q = 0; q < 17; q++) {
        const int idx = t + 256 * q;
        if (idx < DD * DD) tv[q] = Wv[idx];
      }
#pragma unroll
      for (int q = 0; q < 17; q++) {
        const int idx = t + 256 * q;
        if (idx < DD * DD) {
          const int j = idx / DD, k = idx - j * DD;
          WkL[k * WST + j] = tv[q];
        }
      }
    }
    __syncthreads();

    {  // T phase
      const float* WvT = WkL;
      float t0 = 0.f, t1 = 0.f, t2 = 0.f;
      for (int k = 0; k < DD; k++) {
        const float rv = Rr[ty * ST + k];
        t0 = fmaf(rv, WvT[k * WST + tx], t0);
        t1 = fmaf(rv, WvT[k * WST + tx + 32], t1);
        t2 = fmaf(rv, WvT[k * WST + 64], t2);
      }
      if (alive) {
        float* Tb = Tm + (size_t)b * TILE + (size_t)i * ST;
        Tb[tx] = t0;
        Tb[tx + 32] = t1;
        if (tx == 0) Tb[64] = t2;
      }
    }
  }
  cg::this_grid().sync();

  // ================= P3: out = x @ T[b] (R5 k3) =================
  {
    float* Tl = (float*)smem;            // [65][ST]
    float* Xl = (float*)(smem + OFF1);   // [64][ST], reused as Ol
    const int tx = t & 15, ty = t >> 4;
    const int wid = t >> 6, lane = t & 63;
    const int b = bid >> 5;              // 32 blocks per batch
    const int rb = (bid & 31) * 64;
    const float4* Tg4 = (const float4*)(Tm + (size_t)b * TILE);
    const float4* src4 = (const float4*)(x + ((size_t)b * NN + rb) * DD);

    // async stage T -> Tl: 1105 float4 slots
#pragma unroll
    for (int q = 0; q < 4; q++) {
      const int s = q * 256 + wid * 64 + lane;          // < 1024
      GL2LDS(Tg4 + s, Tl + (size_t)(q * 256 + wid * 64) * 4);
    }
    {
      const int s = 1024 + wid * 64 + lane;             // tail: 81 slots
      if (s < TILE / 4) GL2LDS(Tg4 + s, Tl + (size_t)(1024 + wid * 64) * 4);
    }

    // f4 stage x chunk -> Xl (L2-warm from P1: same block, same XCD)
    {
      float4 tmp[5];
#pragma unroll
      for (int q = 0; q < 5; q++) {
        const int i4 = t + 256 * q;
        if (i4 < 1040) tmp[q] = src4[i4];
      }
#pragma unroll
      for (int q = 0; q < 5; q++) {
        const int i4 = t + 256 * q;
        if (i4 < 1040) {
          const int f = 4 * i4;
          const float vv[4] = {tmp[q].x, tmp[q].y, tmp[q].z, tmp[q].w};
#pragma unroll
          for (int j = 0; j < 4; j++) {
            const int r = (f + j) / DD, cc = (f + j) - r * DD;
            Xl[r * ST + cc] = vv[j];
          }
        }
      }
    }
    __syncthreads();  // drains vmcnt -> Tl ready too

    float o[4][4] = {}, o64[4] = {};
    for (int kk = 0; kk < 64; kk += 4) {
      float xa4[4][4];  // [r][e]
      float tb4[4][4];  // [e][cc]
      float t64e[4];
#pragma unroll
      for (int r = 0; r < 4; r++)
        *(float4*)xa4[r] = *(const float4*)&Xl[(4 * ty + r) * ST + kk];
#pragma unroll
      for (int e = 0; e < 4; e++)
        *(float4*)tb4[e] = *(const float4*)&Tl[(kk + e) * ST + 4 * tx];
#pragma unroll
      for (int e = 0; e < 4; e++) t64e[e] = Tl[(kk + e) * ST + 64];
#pragma unroll
      for (int e = 0; e < 4; e++) {
#pragma unroll
        for (int r = 0; r < 4; r++)
#pragma unroll
          for (int cc = 0; cc < 4; cc++)
            o[r][cc] = fmaf(xa4[r][e], tb4[e][cc], o[r][cc]);
#pragma unroll
        for (int r = 0; r < 4; r++)
          o64[r] = fmaf(xa4[r][e], t64e[e], o64[r]);
      }
    }
    {  // k = 64 tail
      float xs[4];
#pragma unroll
      for (int r = 0; r < 4; r++) xs[r] = Xl[(4 * ty + r) * ST + 64];
      float tb[4];
      *(float4*)tb = *(const float4*)&Tl[64 * ST + 4 * tx];
      const float t64 = Tl[64 * ST + 64];
#pragma unroll
      for (int r = 0; r < 4; r++) {
#pragma unroll
        for (int cc = 0; cc < 4; cc++)
          o[r][cc] = fmaf(xs[r], tb[cc], o[r][cc]);
        o64[r] = fmaf(xs[r], t64, o64[r]);
      }
    }

    // epilogue: repack through LDS (reuse Xl) for coalesced f4 stores
    __syncthreads();
    float* Ol = Xl;   // unpadded [64][65]
#pragma unroll
    for (int r = 0; r < 4; r++) {
#pragma unroll
      for (int cc = 0; cc < 4; cc++)
        Ol[(4 * ty + r) * DD + 4 * tx + cc] = o[r][cc];
    }
    if (tx == 0) {
#pragma unroll
      for (int r = 0; r < 4; r++) Ol[(4 * ty + r) * DD + 64] = o64[r];
    }
    __syncthreads();
    {
      float4* ob4 = (float4*)(out + ((size_t)b * NN + rb) * DD);
      const float4* Ol4 = (const float4*)Ol;
#pragma unroll
      for (int q = 0; q < 5; q++) {
        const int i4 = t + 256 * q;
        if (i4 < (64 * DD) / 4) ob4[i4] = Ol4[i4];
      }
    }
  }
}

// ===========================================================================
// Fallback path: the round-5 4-kernel pipeline (verbatim), used only if the
// cooperative launch is rejected by the runtime/capture.
// ===========================================================================
__global__ __launch_bounds__(256, 4) void k1_gram(const float* __restrict__ x,
                                                  float* __restrict__ P) {
  __shared__ __align__(16) float Xl[64 * ST];
  const int t = (int)threadIdx.x;
  const int tx = t & 15, ty = t >> 4;
  const int blk = (int)blockIdx.x;
  const int b = blk >> 5, c = blk & 31;
  const float4* src4 =
      (const float4*)(x + ((size_t)b * NN + (size_t)c * 64) * DD);
  {
    float4 tmp[5];
#pragma unroll
    for (int q = 0; q < 5; q++) {
      const int i4 = t + 256 * q;
      if (i4 < 1040) tmp[q] = src4[i4];
    }
#pragma unroll
    for (int q = 0; q < 5; q++) {
      const int i4 = t + 256 * q;
      if (i4 < 1040) {
        const int f = 4 * i4;
        const float vv[4] = {tmp[q].x, tmp[q].y, tmp[q].z, tmp[q].w};
#pragma unroll
        for (int j = 0; j < 4; j++) {
          const int r = (f + j) / DD, cc = (f + j) - r * DD;
          Xl[r * ST + cc] = vv[j];
        }
      }
    }
  }
  __syncthreads();
  float g[4][4] = {}, g64[4] = {};
  float gcc = 0.f;
  for (int n = 0; n < 64; n++) {
    float rowf[4], colf[4];
    *(float4*)rowf = *(const float4*)&Xl[n * ST + 4 * ty];
    *(float4*)colf = *(const float4*)&Xl[n * ST + 4 * tx];
    const float x64 = Xl[n * ST + 64];
#pragma unroll
    for (int r = 0; r < 4; r++)
#pragma unroll
      for (int cc = 0; cc < 4; cc++)
        g[r][cc] = fmaf(rowf[r], colf[cc], g[r][cc]);
#pragma unroll
    for (int cc = 0; cc < 4; cc++) g64[cc] = fmaf(x64, colf[cc], g64[cc]);
    gcc = fmaf(x64, x64, gcc);
  }
  float* Pp = P + (size_t)blk * TILE;
#pragma unroll
  for (int r = 0; r < 4; r++)
    *(float4*)&Pp[(4 * ty + r) * ST + 4 * tx] = *(float4*)g[r];
  if (ty == 0) {
    *(float4*)&Pp[64 * ST + 4 * tx] = *(float4*)g64;
#pragma unroll
    for (int cc = 0; cc < 4; cc++) Pp[(4 * tx + cc) * ST + 64] = g64[cc];
    if (tx == 0) Pp[64 * ST + 64] = gcc;
  }
}

__global__ __launch_bounds__(256) void kred(const float* __restrict__ P,
                                            float* __restrict__ G) {
  const int t = (int)threadIdx.x;
  const int blk = (int)blockIdx.x;
  const int b = blk / 5, s = blk - b * 5;
  const int Q = TILE / 4;
  const int i4 = s * 256 + t;
  if (i4 < Q) {
    const float4* Pb = (const float4*)(P + (size_t)b * CC * TILE);
    float4 acc = make_float4(0.f, 0.f, 0.f, 0.f);
#pragma unroll
    for (int grp = 0; grp < 4; grp++) {
      float4 v[8];
#pragma unroll
      for (int cc = 0; cc < 8; cc++)
        v[cc] = Pb[(size_t)(8 * grp + cc) * Q + i4];
#pragma unroll
      for (int stp = 4; stp >= 1; stp >>= 1)
#pragma unroll
        for (int cc = 0; cc < stp; cc++) v[cc] = f4add(v[cc], v[cc + stp]);
      acc = f4add(acc, v[0]);
    }
    ((float4*)(G + (size_t)b * TILE))[i4] = acc;
  }
}

__global__ __launch_bounds__(256) void k2_chain(
    const float* __restrict__ Wq, const float* __restrict__ Wk,
    const float* __restrict__ Wv, const float* __restrict__ G,
    float* __restrict__ Tm) {
  __shared__ __align__(16) float WqL[HH * ST];
  __shared__ __align__(16) float WkL[HH * ST];
  __shared__ __align__(16) float GL[TILE];
  __shared__ __align__(16) float WvT[TILE];
  __shared__ __align__(16) float Mr[8 * ST];
  __shared__ __align__(16) float Rr[8 * ST];
  const int t = (int)threadIdx.x;
  const int tx = t & 31, ty = t >> 5;
  const int blk = (int)blockIdx.x;
  const int b = blk / 9, rg = blk - b * 9;
  const int i = 8 * rg + ty;
  const bool alive = (i < DD);
  const int ic = alive ? i : 0;
  {
    float tq[17], tk[17];
#pragma unroll
    for (int q = 0; q < 17; q++) {
      const int idx = t + 256 * q;
      if (idx < HH * DD) { tq[q] = Wq[idx]; tk[q] = Wk[idx]; }
    }
#pragma unroll
    for (int q = 0; q < 17; q++) {
      const int idx = t + 256 * q;
      if (idx < HH * DD) {
        const int r = idx / DD, cc = idx - r * DD;
        WqL[r * ST + cc] = tq[q];
        WkL[r * ST + cc] = tk[q];
      }
    }
  }
  {
    const float4* Gb4 = (const float4*)(G + (size_t)b * TILE);
    float4 tG[5];
#pragma unroll
    for (int q = 0; q < 5; q++) {
      const int i4 = t + 256 * q;
      if (i4 < TILE / 4) tG[q] = Gb4[i4];
    }
#pragma unroll
    for (int q = 0; q < 5; q++) {
      const int i4 = t + 256 * q;
      if (i4 < TILE / 4) *((float4*)GL + i4) = tG[q];
    }
  }
  {
    float tv[17];
#pragma unroll
    for (int q = 0; q < 17; q++) {
      const int idx = t + 256 * q;
      if (idx < DD * DD) tv[q] = Wv[idx];
    }
#pragma unroll
    for (int q = 0; q < 17; q++) {
      const int idx = t + 256 * q;
      if (idx < DD * DD) {
        const int j = idx / DD, k = idx - j * DD;
        WvT[k * ST + j] = tv[q];
      }
    }
  }
  __syncthreads();
  {
    float m0 = 0.f, m1 = 0.f, m2 = 0.f;
    for (int h = 0; h < HH; h++) {
      const float wq = WqL[h * ST + ic];
      m0 = fmaf(wq, WkL[h * ST + tx], m0);
      m1 = fmaf(wq, WkL[h * ST + tx + 32], m1);
      m2 = fmaf(wq, WkL[h * ST + 64], m2);
    }
    if (alive) {
      Mr[ty * ST + tx] = m0;
      Mr[ty * ST + tx + 32] = m1;
      if (tx == 0) Mr[ty * ST + 64] = m2;
    }
  }
  __syncthreads();
  {
    float r0 = 0.f, r1 = 0.f, r2 = 0.f;
    for (int k = 0; k < DD; k++) {
      const float mm = Mr[ty * ST + k];
      r0 = fmaf(mm, GL[k * ST + tx], r0);
      r1 = fmaf(mm, GL[k * ST + tx + 32], r1);
      r2 = fmaf(mm, GL[k * ST + 64], r2);
    }
    if (alive) {
      Rr[ty * ST + tx] = r0;
      Rr[ty * ST + tx + 32] = r1;
      if (tx == 0) Rr[ty * ST + 64] = r2;
    }
  }
  __syncthreads();
  {
    float t0 = 0.f, t1 = 0.f, t2 = 0.f;
    for (int k = 0; k < DD; k++) {
      const float rv = Rr[ty * ST + k];
      t0 = fmaf(rv, WvT[k * ST + tx], t0);
      t1 = fmaf(rv, WvT[k * ST + tx + 32], t1);
      t2 = fmaf(rv, WvT[k * ST + 64], t2);
    }
    if (alive) {
      float* Tb = Tm + (size_t)b * TILE + (size_t)i * ST;
      Tb[tx] = t0;
      Tb[tx + 32] = t1;
      if (tx == 0) Tb[64] = t2;
    }
  }
}

__global__ __launch_bounds__(256, 4) void k3_out(const float* __restrict__ x,
                                                 const float* __restrict__ Tt,
                                                 float* __restrict__ out) {
  __shared__ __align__(16) float Tl[TILE];
  __shared__ __align__(16) float Xl[64 * ST];
  const int t = (int)threadIdx.x;
  const int tx = t & 15, ty = t >> 4;
  const int wid = t >> 6, lane = t & 63;
  const int blk = (int)blockIdx.x;
  const int b = blk >> 5;
  const int rb = (blk & 31) * 64;
  const float4* Tg4 = (const float4*)(Tt + (size_t)b * TILE);
  const float4* src4 = (const float4*)(x + ((size_t)b * NN + rb) * DD);
#pragma unroll
  for (int q = 0; q < 4; q++) {
    const int s = q * 256 + wid * 64 + lane;
    GL2LDS(Tg4 + s, Tl + (size_t)(q * 256 + wid * 64) * 4);
  }
  {
    const int s = 1024 + wid * 64 + lane;
    if (s < TILE / 4) GL2LDS(Tg4 + s, Tl + (size_t)(1024 + wid * 64) * 4);
  }
  {
    float4 tmp[5];
#pragma unroll
    for (int q = 0; q < 5; q++) {
      const int i4 = t + 256 * q;
      if (i4 < 1040) tmp[q] = src4[i4];
    }
#pragma unroll
    for (int q = 0; q < 5; q++) {
      const int i4 = t + 256 * q;
      if (i4 < 1040) {
        const int f = 4 * i4;
        const float vv[4] = {tmp[q].x, tmp[q].y, tmp[q].z, tmp[q].w};
#pragma unroll
        for (int j = 0; j < 4; j++) {
          const int r = (f + j) / DD, cc = (f + j) - r * DD;
          Xl[r * ST + cc] = vv[j];
        }
      }
    }
  }
  __syncthreads();
  float o[4][4] = {}, o64[4] = {};
  for (int kk = 0; kk < 64; kk += 4) {
    float xa4[4][4], tb4[4][4], t64e[4];
#pragma unroll
    for (int r = 0; r < 4; r++)
      *(float4*)xa4[r] = *(const float4*)&Xl[(4 * ty + r) * ST + kk];
#pragma unroll
    for (int e = 0; e < 4; e++)
      *(float4*)tb4[e] = *(const float4*)&Tl[(kk + e) * ST + 4 * tx];
#pragma unroll
    for (int e = 0; e < 4; e++) t64e[e] = Tl[(kk + e) * ST + 64];
#pragma unroll
    for (int e = 0; e < 4; e++) {
#pragma unroll
      for (int r = 0; r < 4; r++)
#pragma unroll
        for (int cc = 0; cc < 4; cc++)
          o[r][cc] = fmaf(xa4[r][e], tb4[e][cc], o[r][cc]);
#pragma unroll
      for (int r = 0; r < 4; r++)
        o64[r] = fmaf(xa4[r][e], t64e[e], o64[r]);
    }
  }
  {
    float xs[4];
#pragma unroll
    for (int r = 0; r < 4; r++) xs[r] = Xl[(4 * ty + r) * ST + 64];
    float tb[4];
    *(float4*)tb = *(const float4*)&Tl[64 * ST + 4 * tx];
    const float t64 = Tl[64 * ST + 64];
#pragma unroll
    for (int r = 0; r < 4; r++) {
#pragma unroll
      for (int cc = 0; cc < 4; cc++)
        o[r][cc] = fmaf(xs[r], tb[cc], o[r][cc]);
      o64[r] = fmaf(xs[r], t64, o64[r]);
    }
  }
  __syncthreads();
  float* Ol = Xl;
#pragma unroll
  for (int r = 0; r < 4; r++) {
#pragma unroll
    for (int cc = 0; cc < 4; cc++)
      Ol[(4 * ty + r) * DD + 4 * tx + cc] = o[r][cc];
  }
  if (tx == 0) {
#pragma unroll
    for (int r = 0; r < 4; r++) Ol[(4 * ty + r) * DD + 64] = o64[r];
  }
  __syncthreads();
  {
    float4* ob4 = (float4*)(out + ((size_t)b * NN + rb) * DD);
    const float4* Ol4 = (const float4*)Ol;
#pragma unroll
    for (int q = 0; q < 5; q++) {
      const int i4 = t + 256 * q;
      if (i4 < (64 * DD) / 4) ob4[i4] = Ol4[i4];
    }
  }
}

extern "C" void kernel_launch(void* const* d_in, const int* in_sizes, int n_in,
                              void* d_out, int out_size, void* d_ws,
                              size_t ws_size, hipStream_t stream) {
  const float* x = (const float*)d_in[0];
  const float* Wq = (const float*)d_in[1];
  const float* Wk = (const float*)d_in[2];
  const float* Wv = (const float*)d_in[3];
  float* out = (float*)d_out;

  // Workspace: P[B*32 tiles] (18.1 MB) + G[B tiles] + T[B tiles] (~0.6 MB ea).
  float* P = (float*)d_ws;
  float* G = P + (size_t)BB * CC * TILE;
  float* Tm = G + (size_t)BB * TILE;

  void* kargs[] = {(void*)&x, (void*)&Wq, (void*)&Wk, (void*)&Wv,
                   (void*)&P, (void*)&G, (void*)&Tm, (void*)&out};
  hipError_t err = hipLaunchCooperativeKernel(
      (void*)fused, dim3(BB * CC), dim3(256), kargs, 0, stream);
  if (err != hipSuccess) {
    // fallback: round-5 4-kernel pipeline
    k1_gram<<<BB * CC, 256, 0, stream>>>(x, P);
    kred<<<BB * 5, 256, 0, stream>>>(P, G);
    k2_chain<<<BB * 9, 256, 0, stream>>>(Wq, Wk, Wv, G, Tm);
    k3_out<<<BB * CC, 256, 0, stream>>>(x, Tm, out);
  }
  (void)in_sizes; (void)n_in; (void)out_size; (void)ws_size;
}

// Round 8
// 282.066 us; speedup vs baseline: 1.4882x; 1.4882x over previous
//
#include <hip/hip_runtime.h>

#define BB 32
#define NN 2048
#define DD 65
#define HH 64
#define ST 68                // padded leading dim (16B-aligned float4 frags)
#define TILE (DD * ST)       // 4420 floats per padded 65x65 matrix
#define CC 32                // x chunks per batch (64 rows each)

__device__ __forceinline__ float4 f4add(float4 a, float4 b) {
  return make_float4(a.x + b.x, a.y + b.y, a.z + b.z, a.w + b.w);
}

// async global->LDS, 16B per lane, wave-uniform LDS base + lane*16
#define GL2LDS(g, l)                                             \
  __builtin_amdgcn_global_load_lds(                              \
      (const __attribute__((address_space(1))) void*)(g),        \
      (__attribute__((address_space(3))) void*)(l), 16, 0, 0)

// ===========================================================================
// kA: gram + (last-block-per-batch) reduce + chain. 1024 blocks x 256 thr.
//  - every block: 64-row partial Gram -> P tile (R5 k1 verbatim)
//  - __threadfence(); atomicAdd(cnt[b]); the LAST block (old==31):
//      acquire-fence, reduce 32 P tiles -> G in LDS (kred's exact tree
//      order -> bit-identical), then M=Wq^T Wk, R=M G, T=R Wv^T in-block
//      (round-0-verified chain pattern, same fma order as R5) -> Tm.
// No grid sync (R7 lesson: cg grid.sync ~100us/ea on 8-XCD). No waiting ->
// no deadlock. LDS: 2 x 17680 B regions (Xl|G  and  WkL|M|R) = 35.4 KB.
// ===========================================================================
__global__ __launch_bounds__(256, 4) void kA(
    const float* __restrict__ x, const float* __restrict__ Wq,
    const float* __restrict__ Wk, const float* __restrict__ Wv,
    float* __restrict__ P, float* __restrict__ Tm, int* __restrict__ cnt) {
  __shared__ __align__(16) float smem[2 * TILE];
  __shared__ int s_last;
  float* R0f = smem;          // gram Xl -> G -> WvT
  float* R1f = smem + TILE;   // WkL -> M -> R
  const int t = (int)threadIdx.x;
  const int tx = t & 15, ty = t >> 4;
  const int blk = (int)blockIdx.x;
  const int b = blk >> 5, c = blk & 31;

  // ---------------- phase 1: partial Gram (R5 k1 verbatim) ----------------
  {
    float* Xl = R0f;
    const float4* src4 =
        (const float4*)(x + ((size_t)b * NN + (size_t)c * 64) * DD);
    {  // f4 staging: 1040 float4, 5 slots/thread, all in flight
      float4 tmp[5];
#pragma unroll
      for (int q = 0; q < 5; q++) {
        const int i4 = t + 256 * q;
        if (i4 < 1040) tmp[q] = src4[i4];
      }
#pragma unroll
      for (int q = 0; q < 5; q++) {
        const int i4 = t + 256 * q;
        if (i4 < 1040) {
          const int f = 4 * i4;
          const float vv[4] = {tmp[q].x, tmp[q].y, tmp[q].z, tmp[q].w};
#pragma unroll
          for (int j = 0; j < 4; j++) {
            const int r = (f + j) / DD, cc = (f + j) - r * DD;
            Xl[r * ST + cc] = vv[j];
          }
        }
      }
    }
    __syncthreads();

    float g[4][4] = {};
    float g64[4] = {};
    float gcc = 0.f;
    for (int n = 0; n < 64; n++) {
      float rowf[4], colf[4];
      *(float4*)rowf = *(const float4*)&Xl[n * ST + 4 * ty];
      *(float4*)colf = *(const float4*)&Xl[n * ST + 4 * tx];
      const float x64 = Xl[n * ST + 64];
#pragma unroll
      for (int r = 0; r < 4; r++)
#pragma unroll
        for (int cc = 0; cc < 4; cc++)
          g[r][cc] = fmaf(rowf[r], colf[cc], g[r][cc]);
#pragma unroll
      for (int cc = 0; cc < 4; cc++) g64[cc] = fmaf(x64, colf[cc], g64[cc]);
      gcc = fmaf(x64, x64, gcc);
    }
    float* Pp = P + (size_t)blk * TILE;
#pragma unroll
    for (int r = 0; r < 4; r++)
      *(float4*)&Pp[(4 * ty + r) * ST + 4 * tx] = *(float4*)g[r];
    if (ty == 0) {
      *(float4*)&Pp[64 * ST + 4 * tx] = *(float4*)g64;  // G[64][j]
#pragma unroll
      for (int cc = 0; cc < 4; cc++)
        Pp[(4 * tx + cc) * ST + 64] = g64[cc];          // G[i][64] symmetry
      if (tx == 0) Pp[64 * ST + 64] = gcc;
    }
  }

  // ---------------- arrival counter: last block runs the chain -----------
  __threadfence();          // release: P tile visible device-wide
  __syncthreads();
  if (t == 0) s_last = atomicAdd(&cnt[b], 1);
  __syncthreads();
  if (s_last != CC - 1) return;
  __threadfence();          // acquire: see all 32 P tiles

  // ---------------- reduce 32 P tiles -> G in R0f (kred tree order) ------
  {
    const float4* Pb = (const float4*)(P + (size_t)b * CC * TILE);
    const int Q = TILE / 4;  // 1105
#pragma unroll
    for (int q = 0; q < 5; q++) {
      const int i4 = t + 256 * q;
      if (i4 < Q) {
        float4 acc = make_float4(0.f, 0.f, 0.f, 0.f);
#pragma unroll
        for (int grp = 0; grp < 4; grp++) {
          float4 v[8];
#pragma unroll
          for (int cc = 0; cc < 8; cc++)
            v[cc] = Pb[(size_t)(8 * grp + cc) * Q + i4];
#pragma unroll
          for (int stp = 4; stp >= 1; stp >>= 1)
#pragma unroll
            for (int cc = 0; cc < stp; cc++)
              v[cc] = f4add(v[cc], v[cc + stp]);
          acc = f4add(acc, v[0]);
        }
        ((float4*)R0f)[i4] = acc;
      }
    }
  }
  // ---------------- stage Wk -> R1f [64][ST] ----------------
  {
    const float4* Wk4 = (const float4*)Wk;
    float4 tk[5];
#pragma unroll
    for (int q = 0; q < 5; q++) {
      const int i4 = t + 256 * q;
      if (i4 < 1040) tk[q] = Wk4[i4];
    }
#pragma unroll
    for (int q = 0; q < 5; q++) {
      const int i4 = t + 256 * q;
      if (i4 < 1040) {
        const int f = 4 * i4;
        const float vv[4] = {tk[q].x, tk[q].y, tk[q].z, tk[q].w};
#pragma unroll
        for (int j = 0; j < 4; j++) {
          const int r = (f + j) / DD, cc = (f + j) - r * DD;
          R1f[r * ST + cc] = vv[j];
        }
      }
    }
  }
  __syncthreads();

  // ---------------- M = Wq^T Wk (Wq from global, broadcast/L1) -----------
  float m[4][4] = {}, mrow[4] = {}, mcol[4] = {};
  float mcc = 0.f;
  for (int h = 0; h < HH; h++) {
    float kb[4];
    *(float4*)kb = *(const float4*)&R1f[h * ST + 4 * tx];
    const float k64 = R1f[h * ST + 64];
    float qa[4];
#pragma unroll
    for (int r = 0; r < 4; r++) qa[r] = Wq[h * DD + 4 * ty + r];
    const float q64 = Wq[h * DD + 64];
#pragma unroll
    for (int r = 0; r < 4; r++)
#pragma unroll
      for (int cc = 0; cc < 4; cc++) m[r][cc] = fmaf(qa[r], kb[cc], m[r][cc]);
#pragma unroll
    for (int cc = 0; cc < 4; cc++) mrow[cc] = fmaf(q64, kb[cc], mrow[cc]);
#pragma unroll
    for (int r = 0; r < 4; r++) mcol[r] = fmaf(qa[r], k64, mcol[r]);
    mcc = fmaf(q64, k64, mcc);
  }
  __syncthreads();  // WkL dead
  // write M -> R1f
#pragma unroll
  for (int r = 0; r < 4; r++)
    *(float4*)&R1f[(4 * ty + r) * ST + 4 * tx] = *(float4*)m[r];
  if (ty == 0) *(float4*)&R1f[64 * ST + 4 * tx] = *(float4*)mrow;
  if (tx == 0) {
#pragma unroll
    for (int r = 0; r < 4; r++) R1f[(4 * ty + r) * ST + 64] = mcol[r];
    if (ty == 0) R1f[64 * ST + 64] = mcc;
  }
  __syncthreads();

  // ---------------- R = M G  (M in R1f, G in R0f) ----------------
  float rr[4][4] = {}, r64j[4] = {}, ri64[4] = {};
  float rcc = 0.f;
  for (int k = 0; k < DD; k++) {
    float gb[4];
    *(float4*)gb = *(const float4*)&R0f[k * ST + 4 * tx];
    const float g64 = R0f[k * ST + 64];
    float ma[4];
#pragma unroll
    for (int r = 0; r < 4; r++) ma[r] = R1f[(4 * ty + r) * ST + k];
    const float m64 = R1f[64 * ST + k];
#pragma unroll
    for (int r = 0; r < 4; r++)
#pragma unroll
      for (int cc = 0; cc < 4; cc++)
        rr[r][cc] = fmaf(ma[r], gb[cc], rr[r][cc]);
#pragma unroll
    for (int cc = 0; cc < 4; cc++) r64j[cc] = fmaf(m64, gb[cc], r64j[cc]);
#pragma unroll
    for (int r = 0; r < 4; r++) ri64[r] = fmaf(ma[r], g64, ri64[r]);
    rcc = fmaf(m64, g64, rcc);
  }
  // issue Wv loads early (written after sync)
  float tv[17];
#pragma unroll
  for (int q = 0; q < 17; q++) {
    const int idx = t + 256 * q;
    if (idx < DD * DD) tv[q] = Wv[idx];
  }
  __syncthreads();  // M dead, G dead
  // write R -> R1f; scatter WvT -> R0f
#pragma unroll
  for (int r = 0; r < 4; r++)
    *(float4*)&R1f[(4 * ty + r) * ST + 4 * tx] = *(float4*)rr[r];
  if (ty == 0) *(float4*)&R1f[64 * ST + 4 * tx] = *(float4*)r64j;
  if (tx == 0) {
#pragma unroll
    for (int r = 0; r < 4; r++) R1f[(4 * ty + r) * ST + 64] = ri64[r];
    if (ty == 0) R1f[64 * ST + 64] = rcc;
  }
#pragma unroll
  for (int q = 0; q < 17; q++) {
    const int idx = t + 256 * q;
    if (idx < DD * DD) {
      const int j = idx / DD, k = idx - j * DD;
      R0f[k * ST + j] = tv[q];  // WvT[k][j] = Wv[j][k]
    }
  }
  __syncthreads();

  // ---------------- T = R Wv^T -> Tm[b] ----------------
  float tt[4][4] = {}, row64[4] = {}, col64[4] = {};
  float tcc = 0.f;
  for (int k = 0; k < DD; k++) {
    float wv[4];
    *(float4*)wv = *(const float4*)&R0f[k * ST + 4 * tx];
    const float w64 = R0f[k * ST + 64];
    float ra[4];
#pragma unroll
    for (int r = 0; r < 4; r++) ra[r] = R1f[(4 * ty + r) * ST + k];
    const float r64 = R1f[64 * ST + k];
#pragma unroll
    for (int r = 0; r < 4; r++)
#pragma unroll
      for (int cc = 0; cc < 4; cc++)
        tt[r][cc] = fmaf(ra[r], wv[cc], tt[r][cc]);
#pragma unroll
    for (int cc = 0; cc < 4; cc++) row64[cc] = fmaf(r64, wv[cc], row64[cc]);
#pragma unroll
    for (int r = 0; r < 4; r++) col64[r] = fmaf(ra[r], w64, col64[r]);
    tcc = fmaf(r64, w64, tcc);
  }
  float* Tb = Tm + (size_t)b * TILE;
#pragma unroll
  for (int r = 0; r < 4; r++)
    *(float4*)&Tb[(4 * ty + r) * ST + 4 * tx] = *(float4*)tt[r];
  if (ty == 0) *(float4*)&Tb[64 * ST + 4 * tx] = *(float4*)row64;  // T[64][j]
  if (tx == 0) {
#pragma unroll
    for (int r = 0; r < 4; r++) Tb[(4 * ty + r) * ST + 64] = col64[r];
    if (ty == 0) Tb[64 * ST + 64] = tcc;
  }
}

// ===========================================================================
// kB: out[b] = x[b] @ T[b] (R5 k3 verbatim). 1024 blocks, lb(256,4), async
// GL2LDS for Tl, f4 staging for Xl, LDS repack epilogue for f4 stores.
// ===========================================================================
__global__ __launch_bounds__(256, 4) void kB(const float* __restrict__ x,
                                             const float* __restrict__ Tt,
                                             float* __restrict__ out) {
  __shared__ __align__(16) float Tl[TILE];       // 17680 B
  __shared__ __align__(16) float Xl[64 * ST];    // 17408 B (reused as Ol)
  const int t = (int)threadIdx.x;
  const int tx = t & 15, ty = t >> 4;
  const int wid = t >> 6, lane = t & 63;
  const int blk = (int)blockIdx.x;
  const int b = blk >> 5;           // 32 blocks per batch
  const int rb = (blk & 31) * 64;
  const float4* Tg4 = (const float4*)(Tt + (size_t)b * TILE);
  const float4* src4 = (const float4*)(x + ((size_t)b * NN + rb) * DD);

#pragma unroll
  for (int q = 0; q < 4; q++) {
    const int s = q * 256 + wid * 64 + lane;          // < 1024
    GL2LDS(Tg4 + s, Tl + (size_t)(q * 256 + wid * 64) * 4);
  }
  {
    const int s = 1024 + wid * 64 + lane;             // tail: 81 slots
    if (s < TILE / 4) GL2LDS(Tg4 + s, Tl + (size_t)(1024 + wid * 64) * 4);
  }
  {
    float4 tmp[5];
#pragma unroll
    for (int q = 0; q < 5; q++) {
      const int i4 = t + 256 * q;
      if (i4 < 1040) tmp[q] = src4[i4];
    }
#pragma unroll
    for (int q = 0; q < 5; q++) {
      const int i4 = t + 256 * q;
      if (i4 < 1040) {
        const int f = 4 * i4;
        const float vv[4] = {tmp[q].x, tmp[q].y, tmp[q].z, tmp[q].w};
#pragma unroll
        for (int j = 0; j < 4; j++) {
          const int r = (f + j) / DD, cc = (f + j) - r * DD;
          Xl[r * ST + cc] = vv[j];
        }
      }
    }
  }
  __syncthreads();  // drains vmcnt -> Tl ready too

  float o[4][4] = {}, o64[4] = {};
  for (int kk = 0; kk < 64; kk += 4) {
    float xa4[4][4], tb4[4][4], t64e[4];
#pragma unroll
    for (int r = 0; r < 4; r++)
      *(float4*)xa4[r] = *(const float4*)&Xl[(4 * ty + r) * ST + kk];
#pragma unroll
    for (int e = 0; e < 4; e++)
      *(float4*)tb4[e] = *(const float4*)&Tl[(kk + e) * ST + 4 * tx];
#pragma unroll
    for (int e = 0; e < 4; e++) t64e[e] = Tl[(kk + e) * ST + 64];
#pragma unroll
    for (int e = 0; e < 4; e++) {
#pragma unroll
      for (int r = 0; r < 4; r++)
#pragma unroll
        for (int cc = 0; cc < 4; cc++)
          o[r][cc] = fmaf(xa4[r][e], tb4[e][cc], o[r][cc]);
#pragma unroll
      for (int r = 0; r < 4; r++)
        o64[r] = fmaf(xa4[r][e], t64e[e], o64[r]);
    }
  }
  {  // k = 64 tail
    float xs[4];
#pragma unroll
    for (int r = 0; r < 4; r++) xs[r] = Xl[(4 * ty + r) * ST + 64];
    float tb[4];
    *(float4*)tb = *(const float4*)&Tl[64 * ST + 4 * tx];
    const float t64 = Tl[64 * ST + 64];
#pragma unroll
    for (int r = 0; r < 4; r++) {
#pragma unroll
      for (int cc = 0; cc < 4; cc++)
        o[r][cc] = fmaf(xs[r], tb[cc], o[r][cc]);
      o64[r] = fmaf(xs[r], t64, o64[r]);
    }
  }

  __syncthreads();
  float* Ol = Xl;   // unpadded [64][65]
#pragma unroll
  for (int r = 0; r < 4; r++) {
#pragma unroll
    for (int cc = 0; cc < 4; cc++)
      Ol[(4 * ty + r) * DD + 4 * tx + cc] = o[r][cc];
  }
  if (tx == 0) {
#pragma unroll
    for (int r = 0; r < 4; r++) Ol[(4 * ty + r) * DD + 64] = o64[r];
  }
  __syncthreads();
  {
    float4* ob4 = (float4*)(out + ((size_t)b * NN + rb) * DD);
    const float4* Ol4 = (const float4*)Ol;
#pragma unroll
    for (int q = 0; q < 5; q++) {
      const int i4 = t + 256 * q;
      if (i4 < (64 * DD) / 4) ob4[i4] = Ol4[i4];
    }
  }
}

extern "C" void kernel_launch(void* const* d_in, const int* in_sizes, int n_in,
                              void* d_out, int out_size, void* d_ws,
                              size_t ws_size, hipStream_t stream) {
  const float* x = (const float*)d_in[0];
  const float* Wq = (const float*)d_in[1];
  const float* Wk = (const float*)d_in[2];
  const float* Wv = (const float*)d_in[3];
  float* out = (float*)d_out;

  // Workspace: P[1024 tiles] (18.1 MB) + Tm[32 tiles] (0.57 MB) + cnt[32].
  float* P = (float*)d_ws;
  float* Tm = P + (size_t)BB * CC * TILE;
  int* cnt = (int*)(Tm + (size_t)BB * TILE);

  hipMemsetAsync(cnt, 0, BB * sizeof(int), stream);
  kA<<<BB * CC, 256, 0, stream>>>(x, Wq, Wk, Wv, P, Tm, cnt);
  kB<<<BB * CC, 256, 0, stream>>>(x, Tm, out);
  (void)in_sizes; (void)n_in; (void)out_size; (void)ws_size;
}

// Round 9
// 123.812 us; speedup vs baseline: 3.3904x; 2.2782x over previous
//
#include <hip/hip_runtime.h>

#define BB 32
#define NN 2048
#define DD 65
#define HH 64
#define ST 68                // padded leading dim (16B-aligned float4 frags)
#define TILE (DD * ST)       // 4420 floats per padded 65x65 matrix
#define CC 32                // x chunks per batch (64 rows each)

__device__ __forceinline__ float4 f4add(float4 a, float4 b) {
  return make_float4(a.x + b.x, a.y + b.y, a.z + b.z, a.w + b.w);
}

// async global->LDS, 16B per lane, wave-uniform LDS base + lane*16
#define GL2LDS(g, l)                                             \
  __builtin_amdgcn_global_load_lds(                              \
      (const __attribute__((address_space(1))) void*)(g),        \
      (__attribute__((address_space(3))) void*)(l), 16, 0, 0)

// ---------------------------------------------------------------------------
// k1: partial Gram P[b][c] = Xc^T Xc, 64-row chunk. 1024 blocks x 256 thr
// (4 blocks/CU, 16 waves/CU -- R5's TLP). N-SPLIT 8x8: each of the 4 waves
// covers the FULL 65x65 tile with 8x8 regs, accumulating over n in
// [16w,16w+16) -> LDS cost/FMA drops 2.5x vs 4x4 (30cyc/21fma -> 54cyc/73fma)
// while keeping 4 waves/SIMD (R3/R4's 8x8 died from TLP loss / 2x P traffic;
// this keeps both). 3-round combine through a dead-LDS buffer, deterministic.
// ---------------------------------------------------------------------------
__global__ __launch_bounds__(256, 4) void k1_gram(const float* __restrict__ x,
                                                  float* __restrict__ P) {
  __shared__ __align__(16) float Xl[64 * ST];   // 17408 B
  __shared__ __align__(16) float Buf[TILE];     // 17680 B combine buffer
  const int t = (int)threadIdx.x;
  const int w = t >> 6, lane = t & 63;
  const int tx8 = lane & 7, ty8 = lane >> 3;
  const int blk = (int)blockIdx.x;
  const int b = blk >> 5, c = blk & 31;
  const float4* src4 =
      (const float4*)(x + ((size_t)b * NN + (size_t)c * 64) * DD);

  {  // f4 staging: 1040 float4, 5 slots/thread, all in flight (R5 verbatim)
    float4 tmp[5];
#pragma unroll
    for (int q = 0; q < 5; q++) {
      const int i4 = t + 256 * q;
      if (i4 < 1040) tmp[q] = src4[i4];
    }
#pragma unroll
    for (int q = 0; q < 5; q++) {
      const int i4 = t + 256 * q;
      if (i4 < 1040) {
        const int f = 4 * i4;
        const float vv[4] = {tmp[q].x, tmp[q].y, tmp[q].z, tmp[q].w};
#pragma unroll
        for (int j = 0; j < 4; j++) {
          const int r = (f + j) / DD, cc = (f + j) - r * DD;
          Xl[r * ST + cc] = vv[j];
        }
      }
    }
  }
  __syncthreads();

  // partial Gram over n in [16w, 16w+16), 8x8 regs (R3-verified body)
  float g[8][8] = {};
  float f64[8] = {};
  float gcc = 0.f;
  for (int n = 16 * w; n < 16 * w + 16; n++) {
    float rowf[8], colf[8];
    *(float4*)&rowf[0] = *(const float4*)&Xl[n * ST + 8 * ty8];
    *(float4*)&rowf[4] = *(const float4*)&Xl[n * ST + 8 * ty8 + 4];
    *(float4*)&colf[0] = *(const float4*)&Xl[n * ST + 8 * tx8];
    *(float4*)&colf[4] = *(const float4*)&Xl[n * ST + 8 * tx8 + 4];
    const float x64 = Xl[n * ST + 64];  // uniform broadcast
#pragma unroll
    for (int r = 0; r < 8; r++)
#pragma unroll
      for (int cc = 0; cc < 8; cc++)
        g[r][cc] = fmaf(rowf[r], colf[cc], g[r][cc]);
#pragma unroll
    for (int cc = 0; cc < 8; cc++) f64[cc] = fmaf(x64, colf[cc], f64[cc]);
    gcc = fmaf(x64, x64, gcc);
  }
  __syncthreads();  // all waves done reading Xl

  // combine: w0 += w1, then += w2, then += w3 (deterministic order)
#pragma unroll 1
  for (int srcw = 1; srcw < 4; srcw++) {
    if (w == srcw) {
#pragma unroll
      for (int r = 0; r < 8; r++) {
        *(float4*)&Buf[(8 * ty8 + r) * ST + 8 * tx8] = *(float4*)&g[r][0];
        *(float4*)&Buf[(8 * ty8 + r) * ST + 8 * tx8 + 4] = *(float4*)&g[r][4];
      }
      if (ty8 == 0) {
#pragma unroll
        for (int cc = 0; cc < 8; cc++) Buf[64 * ST + 8 * tx8 + cc] = f64[cc];
        if (tx8 == 0) Buf[64 * ST + 64] = gcc;
      }
    }
    __syncthreads();
    if (w == 0) {
#pragma unroll
      for (int r = 0; r < 8; r++) {
        float pa[8];
        *(float4*)&pa[0] = *(const float4*)&Buf[(8 * ty8 + r) * ST + 8 * tx8];
        *(float4*)&pa[4] =
            *(const float4*)&Buf[(8 * ty8 + r) * ST + 8 * tx8 + 4];
#pragma unroll
        for (int cc = 0; cc < 8; cc++) g[r][cc] += pa[cc];
      }
#pragma unroll
      for (int cc = 0; cc < 8; cc++) f64[cc] += Buf[64 * ST + 8 * tx8 + cc];
      gcc += Buf[64 * ST + 64];
    }
    __syncthreads();
  }

  if (w == 0) {  // store full tile + edges (R3-verified store)
    float* Pp = P + (size_t)blk * TILE;
#pragma unroll
    for (int r = 0; r < 8; r++) {
      *(float4*)&Pp[(8 * ty8 + r) * ST + 8 * tx8] = *(float4*)&g[r][0];
      *(float4*)&Pp[(8 * ty8 + r) * ST + 8 * tx8 + 4] = *(float4*)&g[r][4];
    }
    if (ty8 == 0) {
#pragma unroll
      for (int cc = 0; cc < 8; cc++) {
        Pp[64 * ST + 8 * tx8 + cc] = f64[cc];        // G[64][j]
        Pp[(8 * tx8 + cc) * ST + 64] = f64[cc];      // G[j][64] by symmetry
      }
      if (tx8 == 0) Pp[64 * ST + 64] = gcc;
    }
  }
}

// ---------------------------------------------------------------------------
// kred: G[b] = sum over 32 chunk tiles of P[b]. 160 blocks (5 per batch),
// one float4 slot per thread, 8 loads in flight + tree sum (x4 groups).
// ---------------------------------------------------------------------------
__global__ __launch_bounds__(256) void kred(const float* __restrict__ P,
                                            float* __restrict__ G) {
  const int t = (int)threadIdx.x;
  const int blk = (int)blockIdx.x;
  const int b = blk / 5, s = blk - b * 5;
  const int Q = TILE / 4;  // 1105
  const int i4 = s * 256 + t;
  if (i4 < Q) {
    const float4* Pb = (const float4*)(P + (size_t)b * CC * TILE);
    float4 acc = make_float4(0.f, 0.f, 0.f, 0.f);
#pragma unroll
    for (int grp = 0; grp < 4; grp++) {
      float4 v[8];
#pragma unroll
      for (int cc = 0; cc < 8; cc++)
        v[cc] = Pb[(size_t)(8 * grp + cc) * Q + i4];
#pragma unroll
      for (int stp = 4; stp >= 1; stp >>= 1)
#pragma unroll
        for (int cc = 0; cc < stp; cc++) v[cc] = f4add(v[cc], v[cc + stp]);
      acc = f4add(acc, v[0]);
    }
    ((float4*)(G + (size_t)b * TILE))[i4] = acc;
  }
}

// ---------------------------------------------------------------------------
// k2b: ROW-PARALLEL chain. T[i,:] = M[i,:] G Wv^T with M = Wq^T Wk.
// 288 blocks (9 row-groups x 32 batches); unchanged (R5).
// ---------------------------------------------------------------------------
__global__ __launch_bounds__(256) void k2_chain(
    const float* __restrict__ Wq, const float* __restrict__ Wk,
    const float* __restrict__ Wv, const float* __restrict__ G,
    float* __restrict__ Tm) {
  __shared__ __align__(16) float WqL[HH * ST];
  __shared__ __align__(16) float WkL[HH * ST];
  __shared__ __align__(16) float GL[TILE];
  __shared__ __align__(16) float WvT[TILE];
  __shared__ __align__(16) float Mr[8 * ST];
  __shared__ __align__(16) float Rr[8 * ST];

  const int t = (int)threadIdx.x;
  const int tx = t & 31, ty = t >> 5;
  const int blk = (int)blockIdx.x;
  const int b = blk / 9, rg = blk - b * 9;
  const int i = 8 * rg + ty;
  const bool alive = (i < DD);
  const int ic = alive ? i : 0;

  {
    float tq[17], tk[17];
#pragma unroll
    for (int q = 0; q < 17; q++) {
      const int idx = t + 256 * q;
      if (idx < HH * DD) { tq[q] = Wq[idx]; tk[q] = Wk[idx]; }
    }
#pragma unroll
    for (int q = 0; q < 17; q++) {
      const int idx = t + 256 * q;
      if (idx < HH * DD) {
        const int r = idx / DD, cc = idx - r * DD;
        WqL[r * ST + cc] = tq[q];
        WkL[r * ST + cc] = tk[q];
      }
    }
  }
  {
    const float4* Gb4 = (const float4*)(G + (size_t)b * TILE);
    float4 tG[5];
#pragma unroll
    for (int q = 0; q < 5; q++) {
      const int i4 = t + 256 * q;
      if (i4 < TILE / 4) tG[q] = Gb4[i4];
    }
#pragma unroll
    for (int q = 0; q < 5; q++) {
      const int i4 = t + 256 * q;
      if (i4 < TILE / 4) *((float4*)GL + i4) = tG[q];
    }
  }
  {
    float tv[17];
#pragma unroll
    for (int q = 0; q < 17; q++) {
      const int idx = t + 256 * q;
      if (idx < DD * DD) tv[q] = Wv[idx];
    }
#pragma unroll
    for (int q = 0; q < 17; q++) {
      const int idx = t + 256 * q;
      if (idx < DD * DD) {
        const int j = idx / DD, k = idx - j * DD;
        WvT[k * ST + j] = tv[q];
      }
    }
  }
  __syncthreads();

  {
    float m0 = 0.f, m1 = 0.f, m2 = 0.f;
    for (int h = 0; h < HH; h++) {
      const float wq = WqL[h * ST + ic];
      m0 = fmaf(wq, WkL[h * ST + tx], m0);
      m1 = fmaf(wq, WkL[h * ST + tx + 32], m1);
      m2 = fmaf(wq, WkL[h * ST + 64], m2);
    }
    if (alive) {
      Mr[ty * ST + tx] = m0;
      Mr[ty * ST + tx + 32] = m1;
      if (tx == 0) Mr[ty * ST + 64] = m2;
    }
  }
  __syncthreads();

  {
    float r0 = 0.f, r1 = 0.f, r2 = 0.f;
    for (int k = 0; k < DD; k++) {
      const float mm = Mr[ty * ST + k];
      r0 = fmaf(mm, GL[k * ST + tx], r0);
      r1 = fmaf(mm, GL[k * ST + tx + 32], r1);
      r2 = fmaf(mm, GL[k * ST + 64], r2);
    }
    if (alive) {
      Rr[ty * ST + tx] = r0;
      Rr[ty * ST + tx + 32] = r1;
      if (tx == 0) Rr[ty * ST + 64] = r2;
    }
  }
  __syncthreads();

  {
    float t0 = 0.f, t1 = 0.f, t2 = 0.f;
    for (int k = 0; k < DD; k++) {
      const float rv = Rr[ty * ST + k];
      t0 = fmaf(rv, WvT[k * ST + tx], t0);
      t1 = fmaf(rv, WvT[k * ST + tx + 32], t1);
      t2 = fmaf(rv, WvT[k * ST + 64], t2);
    }
    if (alive) {
      float* Tb = Tm + (size_t)b * TILE + (size_t)i * ST;
      Tb[tx] = t0;
      Tb[tx + 32] = t1;
      if (tx == 0) Tb[64] = t2;
    }
  }
}

// ---------------------------------------------------------------------------
// k3: out[b] = x[b] @ T[b]. 1024 blocks x 256 thr. K-SPLIT 8x8: each wave
// covers the full 64x65 out-tile with 8x8 regs over k in [16w,16w+16) (w3
// takes the k=64 tail); combine w0+=w1+=w2+=w3 through the dead Xl buffer;
// w0 repacks to unpadded [64][65] and all threads f4-copy out (R5 epilogue).
// Tl async-staged via GL2LDS; Xl f4-staged (both R5 verbatim).
// ---------------------------------------------------------------------------
__global__ __launch_bounds__(256, 4) void k3_out(const float* __restrict__ x,
                                                 const float* __restrict__ Tt,
                                                 float* __restrict__ out) {
  __shared__ __align__(16) float Tl[TILE];       // 17680 B
  __shared__ __align__(16) float Xl[64 * ST];    // 17408 B (-> Buf -> Ol)
  const int t = (int)threadIdx.x;
  const int w = t >> 6, lane = t & 63;
  const int tx8 = lane & 7, ty8 = lane >> 3;
  const int blk = (int)blockIdx.x;
  const int b = blk >> 5;           // 32 blocks per batch
  const int rb = (blk & 31) * 64;
  const float4* Tg4 = (const float4*)(Tt + (size_t)b * TILE);
  const float4* src4 = (const float4*)(x + ((size_t)b * NN + rb) * DD);

  // async stage T -> Tl: 1105 float4 slots (R5 verbatim)
#pragma unroll
  for (int q = 0; q < 4; q++) {
    const int s = q * 256 + w * 64 + lane;            // < 1024
    GL2LDS(Tg4 + s, Tl + (size_t)(q * 256 + w * 64) * 4);
  }
  {
    const int s = 1024 + w * 64 + lane;               // tail: 81 slots
    if (s < TILE / 4) GL2LDS(Tg4 + s, Tl + (size_t)(1024 + w * 64) * 4);
  }
  // f4 stage x chunk -> Xl (R5 verbatim)
  {
    float4 tmp[5];
#pragma unroll
    for (int q = 0; q < 5; q++) {
      const int i4 = t + 256 * q;
      if (i4 < 1040) tmp[q] = src4[i4];
    }
#pragma unroll
    for (int q = 0; q < 5; q++) {
      const int i4 = t + 256 * q;
      if (i4 < 1040) {
        const int f = 4 * i4;
        const float vv[4] = {tmp[q].x, tmp[q].y, tmp[q].z, tmp[q].w};
#pragma unroll
        for (int j = 0; j < 4; j++) {
          const int r = (f + j) / DD, cc = (f + j) - r * DD;
          Xl[r * ST + cc] = vv[j];
        }
      }
    }
  }
  __syncthreads();  // drains vmcnt -> Tl ready too

  float o[8][8] = {}, o64[8] = {};
  const int kbase = 16 * w;
  for (int kk = kbase; kk < kbase + 16; kk += 4) {
    float4 xr[8];  // 4 k-values per row, one b128 each
#pragma unroll
    for (int r = 0; r < 8; r++)
      xr[r] = *(const float4*)&Xl[(8 * ty8 + r) * ST + kk];
    const float* xe[4] = {&xr[0].x, 0, 0, 0};  // (indexed via union below)
    (void)xe;
#pragma unroll
    for (int e = 0; e < 4; e++) {
      const int k = kk + e;
      float tb[8];
      *(float4*)&tb[0] = *(const float4*)&Tl[k * ST + 8 * tx8];
      *(float4*)&tb[4] = *(const float4*)&Tl[k * ST + 8 * tx8 + 4];
      const float t64 = Tl[k * ST + 64];
#pragma unroll
      for (int r = 0; r < 8; r++) {
        const float xv = (e == 0) ? xr[r].x
                       : (e == 1) ? xr[r].y
                       : (e == 2) ? xr[r].z : xr[r].w;
#pragma unroll
        for (int cc = 0; cc < 8; cc++)
          o[r][cc] = fmaf(xv, tb[cc], o[r][cc]);
        o64[r] = fmaf(xv, t64, o64[r]);
      }
    }
  }
  if (w == 3) {  // k = 64 tail
    float tb[8];
    *(float4*)&tb[0] = *(const float4*)&Tl[64 * ST + 8 * tx8];
    *(float4*)&tb[4] = *(const float4*)&Tl[64 * ST + 8 * tx8 + 4];
    const float t64 = Tl[64 * ST + 64];
#pragma unroll
    for (int r = 0; r < 8; r++) {
      const float xv = Xl[(8 * ty8 + r) * ST + 64];
#pragma unroll
      for (int cc = 0; cc < 8; cc++)
        o[r][cc] = fmaf(xv, tb[cc], o[r][cc]);
      o64[r] = fmaf(xv, t64, o64[r]);
    }
  }
  __syncthreads();  // all Xl reads done -> reuse as combine buffer

  float* Buf = Xl;  // [64][ST]; col 64 holds the o64 edge
#pragma unroll 1
  for (int srcw = 1; srcw < 4; srcw++) {
    if (w == srcw) {
#pragma unroll
      for (int r = 0; r < 8; r++) {
        *(float4*)&Buf[(8 * ty8 + r) * ST + 8 * tx8] = *(float4*)&o[r][0];
        *(float4*)&Buf[(8 * ty8 + r) * ST + 8 * tx8 + 4] = *(float4*)&o[r][4];
      }
      if (tx8 == 0) {
#pragma unroll
        for (int r = 0; r < 8; r++) Buf[(8 * ty8 + r) * ST + 64] = o64[r];
      }
    }
    __syncthreads();
    if (w == 0) {
#pragma unroll
      for (int r = 0; r < 8; r++) {
        float pa[8];
        *(float4*)&pa[0] = *(const float4*)&Buf[(8 * ty8 + r) * ST + 8 * tx8];
        *(float4*)&pa[4] =
            *(const float4*)&Buf[(8 * ty8 + r) * ST + 8 * tx8 + 4];
#pragma unroll
        for (int cc = 0; cc < 8; cc++) o[r][cc] += pa[cc];
        o64[r] += Buf[(8 * ty8 + r) * ST + 64];
      }
    }
    __syncthreads();
  }

  // w0 repacks to unpadded [64][65]; all threads copy out as float4
  float* Ol = Xl;
  if (w == 0) {
#pragma unroll
    for (int r = 0; r < 8; r++) {
      const int row = 8 * ty8 + r;
#pragma unroll
      for (int cc = 0; cc < 8; cc++)
        Ol[row * DD + 8 * tx8 + cc] = o[r][cc];
      if (tx8 == 0) Ol[row * DD + 64] = o64[r];
    }
  }
  __syncthreads();
  {
    float4* ob4 = (float4*)(out + ((size_t)b * NN + rb) * DD);
    const float4* Ol4 = (const float4*)Ol;
#pragma unroll
    for (int q = 0; q < 5; q++) {
      const int i4 = t + 256 * q;
      if (i4 < (64 * DD) / 4) ob4[i4] = Ol4[i4];
    }
  }
}

extern "C" void kernel_launch(void* const* d_in, const int* in_sizes, int n_in,
                              void* d_out, int out_size, void* d_ws,
                              size_t ws_size, hipStream_t stream) {
  const float* x = (const float*)d_in[0];
  const float* Wq = (const float*)d_in[1];
  const float* Wk = (const float*)d_in[2];
  const float* Wv = (const float*)d_in[3];
  float* out = (float*)d_out;

  // Workspace: P[B*32 tiles] (18.1 MB) + G[B tiles] + T[B tiles] (~0.6 MB ea).
  float* P = (float*)d_ws;
  float* G = P + (size_t)BB * CC * TILE;
  float* Tm = G + (size_t)BB * TILE;

  k1_gram<<<BB * CC, 256, 0, stream>>>(x, P);
  kred<<<BB * 5, 256, 0, stream>>>(P, G);
  k2_chain<<<BB * 9, 256, 0, stream>>>(Wq, Wk, Wv, G, Tm);
  k3_out<<<BB * CC, 256, 0, stream>>>(x, Tm, out);
  (void)in_sizes; (void)n_in; (void)out_size; (void)ws_size;
}